// Round 13
// baseline (347.337 us; speedup 1.0000x reference)
//
#include <hip/hip_runtime.h>

#define Tn   2048
#define Dn   1024
#define KDn  256
#define NHn  16
#define NKVn 4
#define Rn   4096   // B*T

typedef short bf16x8 __attribute__((ext_vector_type(8)));
typedef float f32x4  __attribute__((ext_vector_type(4)));
typedef const __attribute__((address_space(1))) unsigned* gas_p;
typedef __attribute__((address_space(3))) unsigned* las_p;

// ---- device-global intermediates; referenced ONLY from device code ---------
__device__ unsigned short g_q[(size_t)Rn * Dn];              // [b][t][h][d]
__device__ unsigned short g_k[(size_t)Rn * KDn];             // [b][t][kvh][d]
__device__ unsigned short g_vt[(size_t)2 * NKVn * 64 * Tn];  // [b][kvh][d][t]
__device__ unsigned short g_y[(size_t)Rn * Dn];              // [b][t][h][d]
__device__ unsigned short g_xb[(size_t)Rn * Dn];             // bf16 x
__device__ unsigned short g_wq[(size_t)Dn * Dn];
__device__ unsigned short g_wk[(size_t)KDn * Dn];
__device__ unsigned short g_wv[(size_t)KDn * Dn];
__device__ unsigned short g_wp[(size_t)Dn * Dn];
__device__ float g_tq[Rn * 8];
__device__ float g_tv[Rn * 8];

static __device__ __forceinline__ float bf2f(unsigned short u) {
    return __uint_as_float(((unsigned)u) << 16);
}
static __device__ __forceinline__ unsigned short f2bf(float f) {
    unsigned u = __float_as_uint(f);
    u += 0x7fffu + ((u >> 16) & 1u);   // round-to-nearest-even
    return (unsigned short)(u >> 16);
}
static __device__ __forceinline__ unsigned pk2bf(float a, float b) {
    return (unsigned)f2bf(a) | ((unsigned)f2bf(b) << 16);
}
static __device__ __forceinline__ float wave_sum(float s) {
    #pragma unroll
    for (int off = 32; off; off >>= 1) s += __shfl_xor(s, off);
    return s;
}

// ------- LoRA temporaries tq/tv = x@A^T  +  fused x fp32->bf16 cast ---------
__global__ __launch_bounds__(256)
void lora_tmp(const float* __restrict__ x,
              const float* __restrict__ Aq,
              const float* __restrict__ Av) {
    int tid = threadIdx.x, wave = tid >> 6, lane = tid & 63;
    int row = blockIdx.x * 4 + wave;
    const float2* xr = (const float2*)(x + (size_t)row * Dn);
    unsigned* xbo = (unsigned*)g_xb + (size_t)row * (Dn / 2);
    float aq[8], av[8];
    #pragma unroll
    for (int r = 0; r < 8; r++) { aq[r] = 0.f; av[r] = 0.f; }
    for (int it = 0; it < Dn / 128; it++) {
        int j = it * 64 + lane;
        float2 xv = xr[j];
        xbo[j] = pk2bf(xv.x, xv.y);
        #pragma unroll
        for (int r = 0; r < 8; r++) {
            float2 a2 = ((const float2*)(Aq + (size_t)r * Dn))[j];
            aq[r] += xv.x * a2.x + xv.y * a2.y;
        }
        #pragma unroll
        for (int r = 0; r < 8; r++) {
            float2 a2 = ((const float2*)(Av + (size_t)r * Dn))[j];
            av[r] += xv.x * a2.x + xv.y * a2.y;
        }
    }
    #pragma unroll
    for (int r = 0; r < 8; r++) { aq[r] = wave_sum(aq[r]); av[r] = wave_sum(av[r]); }
    if (lane == 0) {
        #pragma unroll
        for (int r = 0; r < 8; r++) { g_tq[row * 8 + r] = aq[r]; g_tv[row * 8 + r] = av[r]; }
    }
}

// ---------------- single fused weight cast (Wq|Wk|Wv|Wp -> bf16) ------------
#define NQ4 (Dn * Dn / 4)
#define NK4 (KDn * Dn / 4)
__global__ __launch_bounds__(256)
void cast_w(const float* __restrict__ Wq, const float* __restrict__ Wk,
            const float* __restrict__ Wv, const float* __restrict__ Wp) {
    int i = blockIdx.x * 256 + threadIdx.x;
    const float* src; unsigned short* dst; int o;
    if      (i < NQ4)                 { src = Wq; dst = g_wq; o = i; }
    else if (i < NQ4 + NK4)           { src = Wk; dst = g_wk; o = i - NQ4; }
    else if (i < NQ4 + 2 * NK4)       { src = Wv; dst = g_wv; o = i - NQ4 - NK4; }
    else                              { src = Wp; dst = g_wp; o = i - NQ4 - 2 * NK4; }
    float4 v = ((const float4*)src)[o];
    ((uint2*)dst)[o] = make_uint2(pk2bf(v.x, v.y), pk2bf(v.z, v.w));
}

// ---- MFMA GEMM, 128x64 tile, BK=64: 16 MFMA/wave per barrier ---------------
// (r12 had BK=32 = 8 MFMA/barrier; the vmcnt(0) drain before each s_barrier
//  exposed ~500 cyc of prefetch latency per k-step — BK=64 halves barriers.)
// MODE 0 = fused QKV over concatenated N=1536:
//   region 0 (cols 0..1023):    Wq -> +LoRA -> RMSNorm+RoPE+gain -> g_q
//   region 1 (cols 1024..1279): Wk ->          RMSNorm+RoPE       -> g_k
//   region 2 (cols 1280..1535): Wv -> +LoRA -> LDS transpose -> g_vt coalesced
// MODE 1 = out: A=g_y, W=g_wp, C=Cout fp32.
template<int MODE>
__global__ __launch_bounds__(256, 3)
void gemm_bt(float* __restrict__ Cout, const float* __restrict__ BqL,
             const float* __restrict__ BvL, const float* __restrict__ qgain,
             int M, int K) {
    const unsigned short* A = (MODE == 0) ? g_xb : g_y;
    int n0 = blockIdx.x * 64, m0 = blockIdx.y * 128;
    const unsigned short* W;
    int wroff, region;
    if (MODE == 0) {
        if (n0 < 1024)      { W = g_wq; wroff = n0;        region = 0; }
        else if (n0 < 1280) { W = g_wk; wroff = n0 - 1024; region = 1; }
        else                { W = g_wv; wroff = n0 - 1280; region = 2; }
    } else { W = g_wp; wroff = n0; region = 3; }

    // SM shorts: As bufs at 0 / 8192 (128 rows x 64), Ws bufs at 16384 / 20480
    // (64 rows x 64). Region-2 epilogue reuses SM[0..8703] as transpose buffer.
    __shared__ __align__(16) unsigned short SM[24576];
    int tid = threadIdx.x;
    int w = tid >> 6, lane = tid & 63;
    int m_ = lane & 15, quad = lane >> 4;

    // staging: lane -> (row group lane>>3, 16B seg lane&7); wave-uniform base +
    // lane*16B matches gll's LDS scatter exactly (8 rows x 128B per issue)
    int srow = lane >> 3, sseg = (lane & 7) * 8;
    const unsigned short* agp = A + (size_t)(m0 + w * 32 + srow) * K + sseg;
    const unsigned short* wgp = W + (size_t)(wroff + w * 16 + srow) * K + sseg;

    f32x4 acc[2][4];
    #pragma unroll
    for (int im = 0; im < 2; im++)
        #pragma unroll
        for (int in = 0; in < 4; in++) acc[im][in] = (f32x4){0.f, 0.f, 0.f, 0.f};

    // prologue: stage k=0..63 into buffer 0
    #pragma unroll
    for (int i = 0; i < 4; i++)
        __builtin_amdgcn_global_load_lds((gas_p)(agp + (size_t)(i * 8) * K),
                                         (las_p)&SM[(w * 32 + i * 8) * 64], 16, 0, 0);
    #pragma unroll
    for (int i = 0; i < 2; i++)
        __builtin_amdgcn_global_load_lds((gas_p)(wgp + (size_t)(i * 8) * K),
                                         (las_p)&SM[16384 + (w * 16 + i * 8) * 64], 16, 0, 0);

    int nk = K / 64;
    for (int kt = 0; kt < nk; kt++) {
        __syncthreads();
        int cur = kt & 1, nxt = cur ^ 1;
        if (kt + 1 < nk) {
            int ko = (kt + 1) * 64;
            #pragma unroll
            for (int i = 0; i < 4; i++)
                __builtin_amdgcn_global_load_lds((gas_p)(agp + (size_t)(i * 8) * K + ko),
                    (las_p)&SM[nxt * 8192 + (w * 32 + i * 8) * 64], 16, 0, 0);
            #pragma unroll
            for (int i = 0; i < 2; i++)
                __builtin_amdgcn_global_load_lds((gas_p)(wgp + (size_t)(i * 8) * K + ko),
                    (las_p)&SM[16384 + nxt * 4096 + (w * 16 + i * 8) * 64], 16, 0, 0);
        }
        #pragma unroll
        for (int s = 0; s < 2; s++) {
            bf16x8 bf[4];
            #pragma unroll
            for (int in = 0; in < 4; in++)
                bf[in] = *(const bf16x8*)&SM[16384 + cur * 4096 + (in * 16 + m_) * 64 + s * 32 + quad * 8];
            #pragma unroll
            for (int im = 0; im < 2; im++) {
                bf16x8 af = *(const bf16x8*)&SM[cur * 8192 + (w * 32 + im * 16 + m_) * 64 + s * 32 + quad * 8];
                #pragma unroll
                for (int in = 0; in < 4; in++)
                    acc[im][in] = __builtin_amdgcn_mfma_f32_16x16x32_bf16(af, bf[in], acc[im][in], 0, 0, 0);
            }
        }
    }

    if (MODE == 1) {
        #pragma unroll
        for (int im = 0; im < 2; im++)
            #pragma unroll
            for (int r = 0; r < 4; r++) {
                int row = m0 + w * 32 + im * 16 + quad * 4 + r;
                #pragma unroll
                for (int in = 0; in < 4; in++)
                    Cout[(size_t)row * Dn + (n0 + in * 16 + m_)] = acc[im][in][r];
            }
        return;
    }

    if (region <= 1) {
        // ---- fused LoRA(q) + RMSNorm + partial RoPE + gain(q) ----
        float blc[4][8];
        if (region == 0) {
            #pragma unroll
            for (int in = 0; in < 4; in++) {
                const float* bp = BqL + (size_t)(n0 + in * 16 + m_) * 8;
                #pragma unroll
                for (int j = 0; j < 8; j++) blc[in][j] = bp[j];
            }
        }
        float ghead = (region == 0) ? qgain[n0 >> 6] : 1.0f;
        #pragma unroll
        for (int im = 0; im < 2; im++) {
            #pragma unroll
            for (int r = 0; r < 4; r++) {
                int row = m0 + w * 32 + im * 16 + quad * 4 + r;
                float vv[4];
                float ss = 0.f;
                if (region == 0) {
                    const float* tp = g_tq + (size_t)row * 8;
                    float tv8[8];
                    #pragma unroll
                    for (int j = 0; j < 8; j++) tv8[j] = tp[j];
                    #pragma unroll
                    for (int in = 0; in < 4; in++) {
                        float val = acc[im][in][r];
                        #pragma unroll
                        for (int j = 0; j < 8; j++) val += tv8[j] * blc[in][j];
                        vv[in] = val; ss += val * val;
                    }
                } else {
                    #pragma unroll
                    for (int in = 0; in < 4; in++) { vv[in] = acc[im][in][r]; ss += vv[in] * vv[in]; }
                }
                ss += __shfl_xor(ss, 1); ss += __shfl_xor(ss, 2);
                ss += __shfl_xor(ss, 4); ss += __shfl_xor(ss, 8);
                float rs = rsqrtf(ss * (1.0f / 64.0f) + 1.1920929e-7f);
                #pragma unroll
                for (int in = 0; in < 4; in++) vv[in] *= rs;
                float p = __shfl_xor(vv[0], 8);
                int t = row & (Tn - 1);
                float fr = (float)t * exp2f(-(float)(m_ & 7) * 1.6609640474436813f);
                float c = cosf(fr), sn = sinf(fr);
                if (m_ < 16) vv[0] = (m_ < 8) ? vv[0] * c + p * sn : p * sn - vv[0] * c;
                #pragma unroll
                for (int in = 0; in < 4; in++) {
                    float val = vv[in] * ghead;
                    int col = n0 + in * 16 + m_;
                    if (region == 0) g_q[(size_t)row * Dn + col] = f2bf(val);
                    else             g_k[(size_t)row * KDn + (col - 1024)] = f2bf(val);
                }
            }
        }
    } else {
        // ---- region 2: LoRA(v) + LDS transpose -> coalesced g_vt store ----
        float blc[4][8];
        #pragma unroll
        for (int in = 0; in < 4; in++) {
            const float* bp = BvL + (size_t)(n0 - 1280 + in * 16 + m_) * 8;
            #pragma unroll
            for (int j = 0; j < 8; j++) blc[in][j] = bp[j];
        }
        __syncthreads();   // k-loop LDS now dead for all waves
        #pragma unroll
        for (int im = 0; im < 2; im++) {
            #pragma unroll
            for (int r = 0; r < 4; r++) {
                int rl = w * 32 + im * 16 + quad * 4 + r;   // local t
                const float* tp = g_tv + (size_t)(m0 + rl) * 8;
                float tv8[8];
                #pragma unroll
                for (int j = 0; j < 8; j++) tv8[j] = tp[j];
                #pragma unroll
                for (int in = 0; in < 4; in++) {
                    float val = acc[im][in][r];
                    #pragma unroll
                    for (int j = 0; j < 8; j++) val += tv8[j] * blc[in][j];
                    SM[(in * 16 + m_) * 136 + rl] = f2bf(val);  // [d][t], stride 136
                }
            }
        }
        __syncthreads();
        int d = tid >> 2, tseg = (tid & 3) * 32;
        int bb = m0 >> 11, t0 = m0 & (Tn - 1);
        int kvh = (n0 - 1280) >> 6;
        unsigned short* dst = g_vt + (((size_t)(bb * NKVn + kvh) * 64) + d) * Tn + t0 + tseg;
        const uint4* srcv = (const uint4*)&SM[d * 136 + tseg];
        uint4 c0 = srcv[0], c1 = srcv[1], c2 = srcv[2], c3 = srcv[3];
        ((uint4*)dst)[0] = c0; ((uint4*)dst)[1] = c1;
        ((uint4*)dst)[2] = c2; ((uint4*)dst)[3] = c3;
    }
}

// -------- MFMA flash attention, 64-key tiles; KS/VS stride 76 ---------------
// (152B row stride ≡ 6 dw mod 32 -> 16 frag rows land on 16 distinct banks;
//  r12's stride 72 (144B ≡ 4 dw) gave 8-lane aliasing -> 5.9M conflict cyc.)
__global__ __launch_bounds__(256, 3)
void attn_kernel() {
    __shared__ __align__(16) unsigned short KS[2][64 * 76];
    __shared__ __align__(16) unsigned short VS[2][64 * 76];
    __shared__ __align__(16) unsigned short Pt[4][16 * 72];
    const float qsc = 0.125f * 1.44269504088896f;  // 1/sqrt(64) * log2(e)
    int tid = threadIdx.x;
    int w = tid >> 6, lane = tid & 63;
    int q_ = lane & 15, quad = lane >> 4;
    int b = blockIdx.z, kvh = blockIdx.y, h = kvh * 4 + w;
    int qb = blockIdx.x * 16;
    int qg = qb + q_;

    const unsigned short* qrow =
        g_q + ((size_t)(b * Tn + qg) * NHn + h) * 64 + quad * 8;
    bf16x8 Qf0 = *(const bf16x8*)qrow;
    bf16x8 Qf1 = *(const bf16x8*)(qrow + 32);

    int srow = tid >> 2, sseg = (tid & 3) * 16;
    const unsigned short* kgp =
        g_k + ((size_t)(b * Tn + srow) * NKVn + kvh) * 64 + sseg;
    const unsigned short* vgp =
        g_vt + ((size_t)(b * NKVn + kvh) * 64 + srow) * Tn + sseg;

    f32x4 accO[4];
    #pragma unroll
    for (int i = 0; i < 4; i++) accO[i] = (f32x4){0.f, 0.f, 0.f, 0.f};
    float lsum = 0.f;
    int ntiles = (qb + 79) >> 6;

    {
        uint4 ka = *(const uint4*)kgp, kb = *(const uint4*)(kgp + 8);
        uint4 va = *(const uint4*)vgp, vb = *(const uint4*)(vgp + 8);
        *(uint4*)&KS[0][srow * 76 + sseg] = ka;
        *(uint4*)&KS[0][srow * 76 + sseg + 8] = kb;
        *(uint4*)&VS[0][srow * 76 + sseg] = va;
        *(uint4*)&VS[0][srow * 76 + sseg + 8] = vb;
    }
    __syncthreads();

    for (int kt = 0; kt < ntiles; kt++) {
        int cur = kt & 1, nxt = cur ^ 1;
        uint4 kan = make_uint4(0,0,0,0), kbn = kan, van = kan, vbn = kan;
        if (kt + 1 < ntiles) {
            const unsigned short* kp = kgp + (size_t)(kt + 1) * (64 * NKVn * 64);
            const unsigned short* vp = vgp + (kt + 1) * 64;
            kan = *(const uint4*)kp; kbn = *(const uint4*)(kp + 8);
            van = *(const uint4*)vp; vbn = *(const uint4*)(vp + 8);
        }

        const unsigned short* ks = &KS[cur][0];
        const unsigned short* vs = &VS[cur][0];
        f32x4 s[4];
        #pragma unroll
        for (int ss = 0; ss < 4; ss++) {
            bf16x8 ka = *(const bf16x8*)&ks[(ss * 16 + q_) * 76 + quad * 8];
            bf16x8 kb = *(const bf16x8*)&ks[(ss * 16 + q_) * 76 + 32 + quad * 8];
            s[ss] = (f32x4){0.f, 0.f, 0.f, 0.f};
            s[ss] = __builtin_amdgcn_mfma_f32_16x16x32_bf16(ka, Qf0, s[ss], 0, 0, 0);
            s[ss] = __builtin_amdgcn_mfma_f32_16x16x32_bf16(kb, Qf1, s[ss], 0, 0, 0);
        }

        if (kt == ntiles - 1) {
            #pragma unroll
            for (int ss = 0; ss < 4; ss++) {
                int k0 = kt * 64 + ss * 16 + quad * 4;
                #pragma unroll
                for (int r = 0; r < 4; r++)
                    if (k0 + r > qg) s[ss][r] = -1e30f;
            }
        }
        float p[4][4];
        #pragma unroll
        for (int ss = 0; ss < 4; ss++)
            #pragma unroll
            for (int r = 0; r < 4; r++) {
                p[ss][r] = exp2f(s[ss][r] * qsc);
                lsum += p[ss][r];
            }

        unsigned short* pb = &Pt[w][0];
        #pragma unroll
        for (int ss = 0; ss < 4; ss++)
            *(uint2*)&pb[q_ * 72 + ss * 16 + quad * 4] =
                make_uint2(pk2bf(p[ss][0], p[ss][1]), pk2bf(p[ss][2], p[ss][3]));
        bf16x8 pf0 = *(const bf16x8*)&pb[q_ * 72 + quad * 8];
        bf16x8 pf1 = *(const bf16x8*)&pb[q_ * 72 + 32 + quad * 8];

        #pragma unroll
        for (int c = 0; c < 4; c++) {
            bf16x8 vf0 = *(const bf16x8*)&vs[(c * 16 + q_) * 76 + quad * 8];
            bf16x8 vf1 = *(const bf16x8*)&vs[(c * 16 + q_) * 76 + 32 + quad * 8];
            accO[c] = __builtin_amdgcn_mfma_f32_16x16x32_bf16(vf0, pf0, accO[c], 0, 0, 0);
            accO[c] = __builtin_amdgcn_mfma_f32_16x16x32_bf16(vf1, pf1, accO[c], 0, 0, 0);
        }

        if (kt + 1 < ntiles) {
            *(uint4*)&KS[nxt][srow * 76 + sseg] = kan;
            *(uint4*)&KS[nxt][srow * 76 + sseg + 8] = kbn;
            *(uint4*)&VS[nxt][srow * 76 + sseg] = van;
            *(uint4*)&VS[nxt][srow * 76 + sseg + 8] = vbn;
        }
        __syncthreads();
    }

    lsum += __shfl_xor(lsum, 16);
    lsum += __shfl_xor(lsum, 32);
    float invl = 1.0f / lsum;
    unsigned short* yp = g_y + ((size_t)(b * Tn + qg) * NHn + h) * 64;
    #pragma unroll
    for (int c = 0; c < 4; c++) {
        uint2 o = make_uint2(pk2bf(accO[c][0] * invl, accO[c][1] * invl),
                             pk2bf(accO[c][2] * invl, accO[c][3] * invl));
        *(uint2*)&yp[c * 16 + quad * 4] = o;
    }
}

// ----------------------------------------------------------------------------
extern "C" void kernel_launch(void* const* d_in, const int* in_sizes, int n_in,
                              void* d_out, int out_size, void* d_ws, size_t ws_size,
                              hipStream_t stream) {
    const float* x  = (const float*)d_in[0];
    const float* Wq = (const float*)d_in[1];
    const float* Wk = (const float*)d_in[2];
    const float* Wv = (const float*)d_in[3];
    const float* Wp = (const float*)d_in[4];
    const float* qg = (const float*)d_in[5];
    const float* Aq = (const float*)d_in[6];
    const float* Bq = (const float*)d_in[7];
    const float* Av = (const float*)d_in[8];
    const float* Bv = (const float*)d_in[9];
    float* out = (float*)d_out;

    lora_tmp<<<dim3(Rn / 4), dim3(256), 0, stream>>>(x, Aq, Av);
    cast_w<<<dim3((NQ4 * 2 + NK4 * 2) / 256), dim3(256), 0, stream>>>(Wq, Wk, Wv, Wp);
    gemm_bt<0><<<dim3(1536 / 64, Rn / 128), dim3(256), 0, stream>>>(
        nullptr, Bq, Bv, qg, Rn, Dn);
    attn_kernel<<<dim3(Tn / 16, NKVn, 2), dim3(256), 0, stream>>>();
    gemm_bt<1><<<dim3(Dn / 64, Rn / 128), dim3(256), 0, stream>>>(
        out, nullptr, nullptr, nullptr, Rn, Dn);
}